// Round 1
// baseline (1260.675 us; speedup 1.0000x reference)
//
#include <hip/hip_runtime.h>
#include <math.h>

#define B 128
#define V 32
#define H 128

// ---------------------------------------------------------------------------
// Prep: pack transposed weights + combined biases into workspace.
//   wiT[g][k][u] = wi_g[u*V + k]    g: 0=r, 1=z, 2=n   (3 x 32 x 128)
//   whT[g][k][u] = wh_g[u*256 + k]                     (3 x 256 x 128)
//   bias[0][u]=wir_b+whr_b, [1][u]=wiz_b+whz_b, [2][u]=win_b, [3][u]=whn_b
// ---------------------------------------------------------------------------
__global__ void prep_kernel(const float* __restrict__ wir_w, const float* __restrict__ whr_w,
                            const float* __restrict__ wiz_w, const float* __restrict__ whz_w,
                            const float* __restrict__ win_w, const float* __restrict__ whn_w,
                            const float* __restrict__ wir_b, const float* __restrict__ whr_b,
                            const float* __restrict__ wiz_b, const float* __restrict__ whz_b,
                            const float* __restrict__ win_b, const float* __restrict__ whn_b,
                            float* __restrict__ wiT, float* __restrict__ whT,
                            float* __restrict__ bias)
{
    int idx = blockIdx.x * blockDim.x + threadIdx.x;
    int stride = gridDim.x * blockDim.x;
    const int total_wi = 3 * V * H;    // 12288
    const int total_wh = 3 * 256 * H;  // 98304
    for (int t = idx; t < total_wi; t += stride) {
        int g = t / (V * H); int rem = t % (V * H);
        int k = rem / H; int u = rem % H;
        const float* w = (g == 0) ? wir_w : (g == 1) ? wiz_w : win_w;
        wiT[t] = w[u * V + k];
    }
    for (int t = idx; t < total_wh; t += stride) {
        int g = t / (256 * H); int rem = t % (256 * H);
        int k = rem / H; int u = rem % H;
        const float* w = (g == 0) ? whr_w : (g == 1) ? whz_w : whn_w;
        whT[t] = w[u * 256 + k];
    }
    for (int t = idx; t < 4 * H; t += stride) {
        int s = t / H; int u = t % H;
        float v;
        if (s == 0)      v = wir_b[u] + whr_b[u];
        else if (s == 1) v = wiz_b[u] + whz_b[u];
        else if (s == 2) v = win_b[u];
        else             v = whn_b[u];
        bias[t] = v;
    }
}

// ---------------------------------------------------------------------------
// One tree level. Block: 256 threads; tile = 32 rows x 128 units x 3 gates.
// Thread: 4 rows x 4 units, 4 accumulator sets (r, z, in, hn).
// ---------------------------------------------------------------------------
__global__ __launch_bounds__(256) void gru_level_kernel(
    const float* __restrict__ xg,     // targets + start*B*V
    const float* __restrict__ maskg,  // masks + start*B
    const float* __restrict__ prev,   // hidden of level below (2n*B rows) or null
    float* __restrict__ out,          // n*B rows x H
    const float* __restrict__ wiT,
    const float* __restrict__ whT,
    const float* __restrict__ bias,
    int leaf)
{
    __shared__ __attribute__((aligned(16))) float x_lds[32 * 36];
    __shared__ __attribute__((aligned(16))) float h_lds[32 * 260];

    const int tid = threadIdx.x;
    const int Rb = blockIdx.x * 32;   // row base within level
    const int node = Rb >> 7;         // local node index (B=128 rows/node, 32|128)
    const int b0 = Rb & 127;

    // stage x: 32 rows x 32 floats
    {
        int row = tid >> 3;           // 0..31
        int kq = (tid & 7) * 4;       // 0..28
        float4 v = *(const float4*)(xg + (size_t)(Rb + row) * V + kq);
        *(float4*)(&x_lds[row * 36 + kq]) = v;
    }
    // stage h = [h1 | h2]: 32 rows x 256 floats
    if (!leaf) {
        const float* pl = prev + ((size_t)(2 * node) * B + b0) * H;
        const float* pr = prev + ((size_t)(2 * node + 1) * B + b0) * H;
        #pragma unroll
        for (int c = 0; c < 8; ++c) {
            int f4 = c * 256 + tid;
            int row = f4 >> 6;        // 0..31
            int k = (f4 & 63) * 4;    // 0..252
            float4 v;
            if (k < 128) v = *(const float4*)(pl + row * H + k);
            else         v = *(const float4*)(pr + row * H + (k - 128));
            *(float4*)(&h_lds[row * 260 + k]) = v;
        }
    }
    __syncthreads();

    const int jg = tid & 31; const int u0 = jg * 4;
    const int rg = tid >> 5; const int r0 = rg * 4;

    float a_r[4][4], a_z[4][4], a_in[4][4], a_hn[4][4];
    #pragma unroll
    for (int i = 0; i < 4; ++i)
        #pragma unroll
        for (int j = 0; j < 4; ++j) { a_r[i][j] = 0.f; a_z[i][j] = 0.f; a_in[i][j] = 0.f; a_hn[i][j] = 0.f; }

    // ---- input GEMM: K = 32 ----
    #pragma unroll
    for (int k = 0; k < V; k += 4) {
        float4 xv[4];
        #pragma unroll
        for (int rr = 0; rr < 4; ++rr)
            xv[rr] = *(const float4*)(&x_lds[(r0 + rr) * 36 + k]);
        const float* xvf = (const float*)xv;
        #pragma unroll
        for (int kk = 0; kk < 4; ++kk) {
            float4 wr = *(const float4*)(wiT + (size_t)(0 * V + k + kk) * H + u0);
            float4 wz = *(const float4*)(wiT + (size_t)(1 * V + k + kk) * H + u0);
            float4 wn = *(const float4*)(wiT + (size_t)(2 * V + k + kk) * H + u0);
            const float* wrf = (const float*)&wr;
            const float* wzf = (const float*)&wz;
            const float* wnf = (const float*)&wn;
            #pragma unroll
            for (int rr = 0; rr < 4; ++rr) {
                float xval = xvf[rr * 4 + kk];
                #pragma unroll
                for (int uu = 0; uu < 4; ++uu) {
                    a_r[rr][uu]  += xval * wrf[uu];
                    a_z[rr][uu]  += xval * wzf[uu];
                    a_in[rr][uu] += xval * wnf[uu];
                }
            }
        }
    }

    // ---- hidden GEMM: K = 256 ----
    if (!leaf) {
        #pragma unroll 2
        for (int k = 0; k < 256; k += 4) {
            float4 hv[4];
            #pragma unroll
            for (int rr = 0; rr < 4; ++rr)
                hv[rr] = *(const float4*)(&h_lds[(r0 + rr) * 260 + k]);
            const float* hvf = (const float*)hv;
            #pragma unroll
            for (int kk = 0; kk < 4; ++kk) {
                float4 wr = *(const float4*)(whT + (size_t)(0 * 256 + k + kk) * H + u0);
                float4 wz = *(const float4*)(whT + (size_t)(1 * 256 + k + kk) * H + u0);
                float4 wn = *(const float4*)(whT + (size_t)(2 * 256 + k + kk) * H + u0);
                const float* wrf = (const float*)&wr;
                const float* wzf = (const float*)&wz;
                const float* wnf = (const float*)&wn;
                #pragma unroll
                for (int rr = 0; rr < 4; ++rr) {
                    float hval = hvf[rr * 4 + kk];
                    #pragma unroll
                    for (int uu = 0; uu < 4; ++uu) {
                        a_r[rr][uu]  += hval * wrf[uu];
                        a_z[rr][uu]  += hval * wzf[uu];
                        a_hn[rr][uu] += hval * wnf[uu];
                    }
                }
            }
        }
    }

    // ---- epilogue: gate combine + store ----
    float4 br4  = *(const float4*)(bias + 0 * H + u0);
    float4 bz4  = *(const float4*)(bias + 1 * H + u0);
    float4 bin4 = *(const float4*)(bias + 2 * H + u0);
    float4 bhn4 = *(const float4*)(bias + 3 * H + u0);
    const float* br  = (const float*)&br4;
    const float* bz  = (const float*)&bz4;
    const float* bin = (const float*)&bin4;
    const float* bhn = (const float*)&bhn4;

    #pragma unroll
    for (int rr = 0; rr < 4; ++rr) {
        int row = r0 + rr;
        float mval = maskg[Rb + row];
        float4 ho;
        float* hop = (float*)&ho;
        #pragma unroll
        for (int uu = 0; uu < 4; ++uu) {
            float rgate = 1.f / (1.f + expf(-(a_r[rr][uu] + br[uu])));
            float zgate = 1.f / (1.f + expf(-(a_z[rr][uu] + bz[uu])));
            float cgate = tanhf(a_in[rr][uu] + bin[uu] + rgate * (a_hn[rr][uu] + bhn[uu]));
            float h1 = leaf ? 0.f : h_lds[row * 260 + (u0 + uu)];
            float h2 = leaf ? 0.f : h_lds[row * 260 + 128 + (u0 + uu)];
            float hout = (1.f - zgate) * cgate + zgate * 0.5f * (h1 + h2);
            hop[uu] = hout * mval;
        }
        *(float4*)(out + (size_t)(Rb + row) * H + u0) = ho;
    }
}

// ---------------------------------------------------------------------------
// Final projection: mu = root@mu_w.T + mu_b ; logvar = root@lv_w.T + lv_b
// ---------------------------------------------------------------------------
__global__ __launch_bounds__(128) void proj_kernel(
    const float* __restrict__ root,
    const float* __restrict__ mu_w, const float* __restrict__ mu_b,
    const float* __restrict__ lv_w, const float* __restrict__ lv_b,
    float* __restrict__ out)
{
    __shared__ float r_lds[H];
    int b = blockIdx.x;
    int j = threadIdx.x;
    r_lds[j] = root[(size_t)b * H + j];
    __syncthreads();
    float am = 0.f, al = 0.f;
    #pragma unroll 8
    for (int k = 0; k < H; ++k) {
        float rv = r_lds[k];
        am += rv * mu_w[(size_t)j * H + k];
        al += rv * lv_w[(size_t)j * H + k];
    }
    out[(size_t)b * H + j] = am + mu_b[j];
    out[(size_t)(B * H) + (size_t)b * H + j] = al + lv_b[j];
}

// ---------------------------------------------------------------------------
extern "C" void kernel_launch(void* const* d_in, const int* in_sizes, int n_in,
                              void* d_out, int out_size, void* d_ws, size_t ws_size,
                              hipStream_t stream)
{
    const float* targets = (const float*)d_in[0];
    const float* masks   = (const float*)d_in[1];
    const float* wir_w = (const float*)d_in[2];  const float* wir_b = (const float*)d_in[3];
    const float* whr_w = (const float*)d_in[4];  const float* whr_b = (const float*)d_in[5];
    const float* wiz_w = (const float*)d_in[6];  const float* wiz_b = (const float*)d_in[7];
    const float* whz_w = (const float*)d_in[8];  const float* whz_b = (const float*)d_in[9];
    const float* win_w = (const float*)d_in[10]; const float* win_b = (const float*)d_in[11];
    const float* whn_w = (const float*)d_in[12]; const float* whn_b = (const float*)d_in[13];
    const float* mu_w  = (const float*)d_in[14]; const float* mu_b  = (const float*)d_in[15];
    const float* lv_w  = (const float*)d_in[16]; const float* lv_b  = (const float*)d_in[17];

    float* ws = (float*)d_ws;
    float* bufA = ws;                      // 1024*128*128 = 16,777,216 floats (even levels)
    float* bufB = ws + 16777216;           //  512*128*128 =  8,388,608 floats (odd levels)
    float* wiT  = ws + 25165824;           // 3*32*128  = 12,288
    float* whT  = wiT + 3 * 32 * 128;      // 3*256*128 = 98,304
    float* bias = whT + 3 * 256 * 128;     // 4*128     = 512

    prep_kernel<<<64, 256, 0, stream>>>(wir_w, whr_w, wiz_w, whz_w, win_w, whn_w,
                                        wir_b, whr_b, wiz_b, whz_b, win_b, whn_b,
                                        wiT, whT, bias);

    const float* prev = nullptr;
    for (int d = 10; d >= 0; --d) {
        int n = 1 << d;
        int start = n - 1;
        float* outb = (d % 2 == 0) ? bufA : bufB;
        int blocks = (n * B) / 32;
        gru_level_kernel<<<blocks, 256, 0, stream>>>(
            targets + (size_t)start * B * V,
            masks + (size_t)start * B,
            prev, outb, wiT, whT, bias, prev == nullptr ? 1 : 0);
        prev = outb;
    }

    proj_kernel<<<128, 128, 0, stream>>>(bufA, mu_w, mu_b, lv_w, lv_b, (float*)d_out);
}

// Round 2
// 206.347 us; speedup vs baseline: 6.1095x; 6.1095x over previous
//
#include <hip/hip_runtime.h>
#include <hip/hip_bf16.h>
#include <math.h>

#define B 128
#define V 32
#define H 128
#define LDA 296   // padded A row length in bf16 elems (592 B: 2-way-free LDS banks)

typedef __attribute__((ext_vector_type(8))) short bf16x8;
typedef __attribute__((ext_vector_type(4))) float f32x4;

__device__ inline f32x4 mfma_bf16(bf16x8 a, bf16x8 b, f32x4 c) {
    return __builtin_amdgcn_mfma_f32_16x16x32_bf16(a, b, c, 0, 0, 0);
}
__device__ inline unsigned short f2bf(float f) {
    __hip_bfloat16 h = __float2bfloat16(f);
    return __builtin_bit_cast(unsigned short, h);
}
__device__ inline float bf2f(unsigned short u) {
    unsigned int x = ((unsigned int)u) << 16;
    return __builtin_bit_cast(float, x);
}

// ---------------------------------------------------------------------------
// Pack weights into MFMA B-fragment order (bf16) + combined biases (fp32).
// frag index = (ks*24 + ct)*64 + lane, 8 bf16 elems each.
// ct = g*8 + t  (g: 0=r 1=z 2=n; t: unit-tile 0..7, u = t*16 + (lane&15))
// k map (same map used for A-frags, so any consistent HW k-perm cancels):
//   ks==0: k = 8*(lane>>4)+i  (input, K=32);  ks>=1: k = (ks-1)*32 + 8*(lane>>4)+i
// ---------------------------------------------------------------------------
__global__ void prep_pack(const float* __restrict__ wir_w, const float* __restrict__ whr_w,
                          const float* __restrict__ wiz_w, const float* __restrict__ whz_w,
                          const float* __restrict__ win_w, const float* __restrict__ whn_w,
                          const float* __restrict__ wir_b, const float* __restrict__ whr_b,
                          const float* __restrict__ wiz_b, const float* __restrict__ whz_b,
                          const float* __restrict__ win_b, const float* __restrict__ whn_b,
                          unsigned short* __restrict__ wFrag, float* __restrict__ bias)
{
    int idx = blockIdx.x * blockDim.x + threadIdx.x;
    if (idx < 9 * 24 * 64) {
        int lane = idx & 63;
        int ctks = idx >> 6;
        int ct = ctks % 24;
        int ks = ctks / 24;
        int g = ct >> 3;
        int t = ct & 7;
        int u = t * 16 + (lane & 15);
        const float* wi = (g == 0) ? wir_w : (g == 1) ? wiz_w : win_w;
        const float* wh = (g == 0) ? whr_w : (g == 1) ? whz_w : whn_w;
        unsigned short v[8] __attribute__((aligned(16)));
        #pragma unroll
        for (int i = 0; i < 8; ++i) {
            float f;
            if (ks == 0) { int k = 8 * (lane >> 4) + i; f = wi[u * V + k]; }
            else         { int k = (ks - 1) * 32 + 8 * (lane >> 4) + i; f = wh[u * 256 + k]; }
            v[i] = f2bf(f);
        }
        *(int4*)(wFrag + (size_t)idx * 8) = *(const int4*)v;
    }
    if (idx < 4 * H) {
        int s = idx / H, u = idx % H;
        float val;
        if (s == 0)      val = wir_b[u] + whr_b[u];
        else if (s == 1) val = wiz_b[u] + whz_b[u];
        else if (s == 2) val = win_b[u];
        else             val = whn_b[u];
        bias[idx] = val;
    }
}

// ---------------------------------------------------------------------------
// One tree level, MFMA. Block = 256 thr (4 waves), M=32 rows, N=128 units x 4.
// Wave wc owns units [wc*32, wc*32+32): 2 unit-tiles x 2 row-tiles x
// {r, z, in, hn} accumulators. K = 32 (x) + 256 (h1|h2).
// ---------------------------------------------------------------------------
__global__ __launch_bounds__(256) void gru_mfma_kernel(
    const float* __restrict__ xg,
    const float* __restrict__ maskg,
    const unsigned short* __restrict__ prev,   // bf16 hidden of level below
    unsigned short* __restrict__ out,          // bf16 hidden out, n*B x H
    const unsigned short* __restrict__ wFrag,
    const float* __restrict__ bias,
    int leaf)
{
    __shared__ __attribute__((aligned(16))) unsigned short a_lds[32 * LDA];

    const int tid = threadIdx.x;
    const int Rb = blockIdx.x * 32;
    const int node = Rb >> 7;
    const int b0 = Rb & 127;

    // ---- stage x (fp32 -> bf16): 32 rows x 32 ----
    {
        int row = tid >> 3;
        int k4 = (tid & 7) * 4;
        float4 v = *(const float4*)(xg + (size_t)(Rb + row) * V + k4);
        unsigned int lo = (unsigned int)f2bf(v.x) | ((unsigned int)f2bf(v.y) << 16);
        unsigned int hi = (unsigned int)f2bf(v.z) | ((unsigned int)f2bf(v.w) << 16);
        uint2 p; p.x = lo; p.y = hi;
        *(uint2*)(&a_lds[row * LDA + k4]) = p;
    }
    // ---- stage h = [h1|h2] (bf16 copy): 32 rows x 256 ----
    if (!leaf) {
        const unsigned short* pl = prev + ((size_t)(2 * node) * B + b0) * H;
        const unsigned short* pr = prev + ((size_t)(2 * node + 1) * B + b0) * H;
        #pragma unroll
        for (int c = 0; c < 4; ++c) {
            int f = c * 256 + tid;            // 0..1023 chunks of 8 bf16
            int row = f >> 5;
            int chunk = f & 31;
            const unsigned short* src = (chunk < 16) ? (pl + row * H + chunk * 8)
                                                     : (pr + row * H + (chunk - 16) * 8);
            int4 v = *(const int4*)src;
            *(int4*)(&a_lds[row * LDA + 32 + chunk * 8]) = v;
        }
    }
    __syncthreads();

    const int lane = tid & 63;
    const int wc = tid >> 6;       // unit group 0..3
    const int l15 = lane & 15;
    const int lg = lane >> 4;

    f32x4 zero4 = {0.f, 0.f, 0.f, 0.f};
    f32x4 acc_r[2][2], acc_z[2][2], acc_in[2][2], acc_hn[2][2];
    #pragma unroll
    for (int a = 0; a < 2; ++a)
        #pragma unroll
        for (int b = 0; b < 2; ++b) {
            acc_r[a][b] = zero4; acc_z[a][b] = zero4;
            acc_in[a][b] = zero4; acc_hn[a][b] = zero4;
        }

    // ---- K-step 0: input x ----
    {
        bf16x8 a0 = *(const bf16x8*)(&a_lds[l15 * LDA + 8 * lg]);
        bf16x8 a1 = *(const bf16x8*)(&a_lds[(16 + l15) * LDA + 8 * lg]);
        #pragma unroll
        for (int t = 0; t < 2; ++t) {
            int tt = 2 * wc + t;
            bf16x8 br_ = *(const bf16x8*)(wFrag + ((size_t)(tt) * 64 + lane) * 8);
            bf16x8 bz_ = *(const bf16x8*)(wFrag + ((size_t)(8 + tt) * 64 + lane) * 8);
            bf16x8 bn_ = *(const bf16x8*)(wFrag + ((size_t)(16 + tt) * 64 + lane) * 8);
            acc_r[0][t] = mfma_bf16(a0, br_, acc_r[0][t]);
            acc_r[1][t] = mfma_bf16(a1, br_, acc_r[1][t]);
            acc_z[0][t] = mfma_bf16(a0, bz_, acc_z[0][t]);
            acc_z[1][t] = mfma_bf16(a1, bz_, acc_z[1][t]);
            acc_in[0][t] = mfma_bf16(a0, bn_, acc_in[0][t]);
            acc_in[1][t] = mfma_bf16(a1, bn_, acc_in[1][t]);
        }
    }
    // ---- K-steps 1..8: hidden [h1|h2] ----
    if (!leaf) {
        #pragma unroll 2
        for (int ks = 1; ks <= 8; ++ks) {
            bf16x8 a0 = *(const bf16x8*)(&a_lds[l15 * LDA + ks * 32 + 8 * lg]);
            bf16x8 a1 = *(const bf16x8*)(&a_lds[(16 + l15) * LDA + ks * 32 + 8 * lg]);
            size_t fb = (size_t)ks * 24 * 64;
            #pragma unroll
            for (int t = 0; t < 2; ++t) {
                int tt = 2 * wc + t;
                bf16x8 br_ = *(const bf16x8*)(wFrag + (fb + (size_t)(tt) * 64 + lane) * 8);
                bf16x8 bz_ = *(const bf16x8*)(wFrag + (fb + (size_t)(8 + tt) * 64 + lane) * 8);
                bf16x8 bn_ = *(const bf16x8*)(wFrag + (fb + (size_t)(16 + tt) * 64 + lane) * 8);
                acc_r[0][t] = mfma_bf16(a0, br_, acc_r[0][t]);
                acc_r[1][t] = mfma_bf16(a1, br_, acc_r[1][t]);
                acc_z[0][t] = mfma_bf16(a0, bz_, acc_z[0][t]);
                acc_z[1][t] = mfma_bf16(a1, bz_, acc_z[1][t]);
                acc_hn[0][t] = mfma_bf16(a0, bn_, acc_hn[0][t]);
                acc_hn[1][t] = mfma_bf16(a1, bn_, acc_hn[1][t]);
            }
        }
    }

    // ---- epilogue: gate combine + bf16 store ----
    #pragma unroll
    for (int rt = 0; rt < 2; ++rt) {
        #pragma unroll
        for (int t = 0; t < 2; ++t) {
            int u = wc * 32 + t * 16 + l15;
            float br = bias[u];
            float bz = bias[128 + u];
            float bin = bias[256 + u];
            float bhn = bias[384 + u];
            #pragma unroll
            for (int reg = 0; reg < 4; ++reg) {
                int row = rt * 16 + lg * 4 + reg;
                int grow = Rb + row;
                float m = maskg[grow];
                float ar = acc_r[rt][t][reg] + br;
                float az = acc_z[rt][t][reg] + bz;
                float ain = acc_in[rt][t][reg] + bin;
                float ahn = acc_hn[rt][t][reg] + bhn;  // leaf: acc_hn==0 -> r*bhn, matches ref
                float rg = 1.f / (1.f + expf(-ar));
                float zg = 1.f / (1.f + expf(-az));
                float cg = tanhf(ain + rg * ahn);
                float h1 = 0.f, h2 = 0.f;
                if (!leaf) {
                    h1 = bf2f(a_lds[row * LDA + 32 + u]);
                    h2 = bf2f(a_lds[row * LDA + 160 + u]);
                }
                float ho = (1.f - zg) * cg + zg * 0.5f * (h1 + h2);
                out[(size_t)grow * H + u] = f2bf(ho * m);
            }
        }
    }
}

// ---------------------------------------------------------------------------
// Final projection from bf16 root.
// ---------------------------------------------------------------------------
__global__ __launch_bounds__(128) void proj_kernel(
    const unsigned short* __restrict__ root,
    const float* __restrict__ mu_w, const float* __restrict__ mu_b,
    const float* __restrict__ lv_w, const float* __restrict__ lv_b,
    float* __restrict__ out)
{
    __shared__ float r_lds[H];
    int b = blockIdx.x;
    int j = threadIdx.x;
    r_lds[j] = bf2f(root[(size_t)b * H + j]);
    __syncthreads();
    float am = 0.f, al = 0.f;
    #pragma unroll 8
    for (int k = 0; k < H; ++k) {
        float rv = r_lds[k];
        am += rv * mu_w[(size_t)j * H + k];
        al += rv * lv_w[(size_t)j * H + k];
    }
    out[(size_t)b * H + j] = am + mu_b[j];
    out[(size_t)(B * H) + (size_t)b * H + j] = al + lv_b[j];
}

// ---------------------------------------------------------------------------
extern "C" void kernel_launch(void* const* d_in, const int* in_sizes, int n_in,
                              void* d_out, int out_size, void* d_ws, size_t ws_size,
                              hipStream_t stream)
{
    const float* targets = (const float*)d_in[0];
    const float* masks   = (const float*)d_in[1];
    const float* wir_w = (const float*)d_in[2];  const float* wir_b = (const float*)d_in[3];
    const float* whr_w = (const float*)d_in[4];  const float* whr_b = (const float*)d_in[5];
    const float* wiz_w = (const float*)d_in[6];  const float* wiz_b = (const float*)d_in[7];
    const float* whz_w = (const float*)d_in[8];  const float* whz_b = (const float*)d_in[9];
    const float* win_w = (const float*)d_in[10]; const float* win_b = (const float*)d_in[11];
    const float* whn_w = (const float*)d_in[12]; const float* whn_b = (const float*)d_in[13];
    const float* mu_w  = (const float*)d_in[14]; const float* mu_b  = (const float*)d_in[15];
    const float* lv_w  = (const float*)d_in[16]; const float* lv_b  = (const float*)d_in[17];

    unsigned short* bufA  = (unsigned short*)d_ws;          // even levels: up to 1024*128*128 bf16
    unsigned short* bufB  = bufA + 16777216;                // odd levels: up to 512*128*128 bf16
    unsigned short* wFrag = bufB + 8388608;                 // 9*24*64*8 = 110,592 bf16
    float*          biasw = (float*)(wFrag + 110592);       // 4*128 fp32 (4B-aligned offset)

    prep_pack<<<(9 * 24 * 64 + 255) / 256, 256, 0, stream>>>(
        wir_w, whr_w, wiz_w, whz_w, win_w, whn_w,
        wir_b, whr_b, wiz_b, whz_b, win_b, whn_b, wFrag, biasw);

    const unsigned short* prev = nullptr;
    for (int d = 10; d >= 0; --d) {
        int n = 1 << d;
        int start = n - 1;
        unsigned short* outb = (d & 1) ? bufB : bufA;
        int blocks = (n * B) / 32;
        gru_mfma_kernel<<<blocks, 256, 0, stream>>>(
            targets + (size_t)start * B * V,
            masks + (size_t)start * B,
            prev, outb, wFrag, biasw, prev == nullptr ? 1 : 0);
        prev = outb;
    }

    proj_kernel<<<128, 128, 0, stream>>>(bufA, mu_w, mu_b, lv_w, lv_b, (float*)d_out);
}

// Round 3
// 152.437 us; speedup vs baseline: 8.2701x; 1.3537x over previous
//
#include <hip/hip_runtime.h>
#include <hip/hip_bf16.h>
#include <math.h>

#define B 128
#define V 32
#define H 128
#define LDA 296   // padded A row length in bf16 elems (592 B row pitch)

typedef __attribute__((ext_vector_type(8))) short bf16x8;
typedef __attribute__((ext_vector_type(4))) float f32x4;

__device__ inline f32x4 mfma_bf16(bf16x8 a, bf16x8 b, f32x4 c) {
    return __builtin_amdgcn_mfma_f32_16x16x32_bf16(a, b, c, 0, 0, 0);
}
__device__ inline unsigned short f2bf(float f) {
    __hip_bfloat16 h = __float2bfloat16(f);
    return __builtin_bit_cast(unsigned short, h);
}
__device__ inline float bf2f(unsigned short u) {
    unsigned int x = ((unsigned int)u) << 16;
    return __builtin_bit_cast(float, x);
}
// fast activations: v_exp_f32 + v_rcp_f32 (2 trans ops each, ~1-ulp)
__device__ inline float fast_sigmoid(float x) {
    float e = __builtin_amdgcn_exp2f(x * -1.44269504f);
    return __builtin_amdgcn_rcpf(1.f + e);
}
__device__ inline float fast_tanh(float x) {
    float e = __builtin_amdgcn_exp2f(x * 2.88539008f);   // exp(2x)
    return 1.f - 2.f * __builtin_amdgcn_rcpf(e + 1.f);
}

// ---------------------------------------------------------------------------
// Pack weights into MFMA B-fragment order (bf16) + combined biases (fp32).
// frag index = (ks*24 + ct)*64 + lane; ct = g*8 + t (g: 0=r 1=z 2=n).
// Same (lane,elem)->k map as the A-frags, so any HW k-permutation cancels.
// ---------------------------------------------------------------------------
__global__ void prep_pack(const float* __restrict__ wir_w, const float* __restrict__ whr_w,
                          const float* __restrict__ wiz_w, const float* __restrict__ whz_w,
                          const float* __restrict__ win_w, const float* __restrict__ whn_w,
                          const float* __restrict__ wir_b, const float* __restrict__ whr_b,
                          const float* __restrict__ wiz_b, const float* __restrict__ whz_b,
                          const float* __restrict__ win_b, const float* __restrict__ whn_b,
                          unsigned short* __restrict__ wFrag, float* __restrict__ bias)
{
    int idx = blockIdx.x * blockDim.x + threadIdx.x;
    if (idx < 9 * 24 * 64) {
        int lane = idx & 63;
        int ctks = idx >> 6;
        int ct = ctks % 24;
        int ks = ctks / 24;
        int g = ct >> 3;
        int t = ct & 7;
        int u = t * 16 + (lane & 15);
        const float* wi = (g == 0) ? wir_w : (g == 1) ? wiz_w : win_w;
        const float* wh = (g == 0) ? whr_w : (g == 1) ? whz_w : whn_w;
        unsigned short v[8] __attribute__((aligned(16)));
        #pragma unroll
        for (int i = 0; i < 8; ++i) {
            float f;
            if (ks == 0) { int k = 8 * (lane >> 4) + i; f = wi[u * V + k]; }
            else         { int k = (ks - 1) * 32 + 8 * (lane >> 4) + i; f = wh[u * 256 + k]; }
            v[i] = f2bf(f);
        }
        *(int4*)(wFrag + (size_t)idx * 8) = *(const int4*)v;
    }
    if (idx < 4 * H) {
        int s = idx / H, u = idx % H;
        float val;
        if (s == 0)      val = wir_b[u] + whr_b[u];
        else if (s == 1) val = wiz_b[u] + whz_b[u];
        else if (s == 2) val = win_b[u];
        else             val = whn_b[u];
        bias[idx] = val;
    }
}

// ---------------------------------------------------------------------------
// One tree level, MFMA. Block = 512 thr (8 waves), M=64 rows.
// Wave w: wr=w>>2 (row half), wc=w&3 (unit group of 32). Each wave:
// 2 row-tiles x 2 unit-tiles x {r,z,in,hn} f32x4 accumulators.
// ---------------------------------------------------------------------------
__global__ __launch_bounds__(512) void gru_mfma_kernel(
    const float* __restrict__ xg,
    const float* __restrict__ maskg,
    const unsigned short* __restrict__ prev,   // bf16 hidden of level below
    unsigned short* __restrict__ out,          // bf16 hidden out, n*B x H
    const unsigned short* __restrict__ wFrag,
    const float* __restrict__ bias,
    int leaf)
{
    __shared__ __attribute__((aligned(16))) unsigned short a_lds[64 * LDA]; // 37888 B

    const int tid = threadIdx.x;
    const int Rb = blockIdx.x * 64;
    const int node = Rb >> 7;          // 64-row block lies within one node (64|128)
    const int b0 = Rb & 127;

    // ---- stage x (fp32 -> bf16): 64 rows x 32 ----
    {
        int row = tid >> 3;
        int k4 = (tid & 7) * 4;
        float4 v = *(const float4*)(xg + (size_t)(Rb + row) * V + k4);
        unsigned int lo = (unsigned int)f2bf(v.x) | ((unsigned int)f2bf(v.y) << 16);
        unsigned int hi = (unsigned int)f2bf(v.z) | ((unsigned int)f2bf(v.w) << 16);
        uint2 p; p.x = lo; p.y = hi;
        *(uint2*)(&a_lds[row * LDA + k4]) = p;
    }
    // ---- stage h = [h1|h2] (bf16 copy): 64 rows x 256 ----
    if (!leaf) {
        const unsigned short* pl = prev + ((size_t)(2 * node) * B + b0) * H;
        const unsigned short* pr = prev + ((size_t)(2 * node + 1) * B + b0) * H;
        #pragma unroll
        for (int c = 0; c < 4; ++c) {
            int f = c * 512 + tid;            // 2048 chunks of 8 bf16
            int row = f >> 5;                 // 0..63
            int chunk = f & 31;
            const unsigned short* src = (chunk < 16) ? (pl + row * H + chunk * 8)
                                                     : (pr + row * H + (chunk - 16) * 8);
            int4 v = *(const int4*)src;
            *(int4*)(&a_lds[row * LDA + 32 + chunk * 8]) = v;
        }
    }
    __syncthreads();

    const int lane = tid & 63;
    const int w = tid >> 6;
    const int wc = w & 3;          // unit group 0..3
    const int rbase = (w >> 2) * 32;  // row half 0 / 32
    const int l15 = lane & 15;
    const int lg = lane >> 4;

    f32x4 zero4 = {0.f, 0.f, 0.f, 0.f};
    f32x4 acc_r[2][2], acc_z[2][2], acc_in[2][2], acc_hn[2][2];
    #pragma unroll
    for (int a = 0; a < 2; ++a)
        #pragma unroll
        for (int b = 0; b < 2; ++b) {
            acc_r[a][b] = zero4; acc_z[a][b] = zero4;
            acc_in[a][b] = zero4; acc_hn[a][b] = zero4;
        }

    // ---- K-step 0: input x ----
    {
        bf16x8 a0 = *(const bf16x8*)(&a_lds[(rbase + l15) * LDA + 8 * lg]);
        bf16x8 a1 = *(const bf16x8*)(&a_lds[(rbase + 16 + l15) * LDA + 8 * lg]);
        #pragma unroll
        for (int t = 0; t < 2; ++t) {
            int tt = 2 * wc + t;
            bf16x8 br_ = *(const bf16x8*)(wFrag + ((size_t)(tt) * 64 + lane) * 8);
            bf16x8 bz_ = *(const bf16x8*)(wFrag + ((size_t)(8 + tt) * 64 + lane) * 8);
            bf16x8 bn_ = *(const bf16x8*)(wFrag + ((size_t)(16 + tt) * 64 + lane) * 8);
            acc_r[0][t] = mfma_bf16(a0, br_, acc_r[0][t]);
            acc_r[1][t] = mfma_bf16(a1, br_, acc_r[1][t]);
            acc_z[0][t] = mfma_bf16(a0, bz_, acc_z[0][t]);
            acc_z[1][t] = mfma_bf16(a1, bz_, acc_z[1][t]);
            acc_in[0][t] = mfma_bf16(a0, bn_, acc_in[0][t]);
            acc_in[1][t] = mfma_bf16(a1, bn_, acc_in[1][t]);
        }
    }
    // ---- K-steps 1..8: hidden [h1|h2] ----
    if (!leaf) {
        #pragma unroll 2
        for (int ks = 1; ks <= 8; ++ks) {
            bf16x8 a0 = *(const bf16x8*)(&a_lds[(rbase + l15) * LDA + ks * 32 + 8 * lg]);
            bf16x8 a1 = *(const bf16x8*)(&a_lds[(rbase + 16 + l15) * LDA + ks * 32 + 8 * lg]);
            size_t fb = (size_t)ks * 24 * 64;
            #pragma unroll
            for (int t = 0; t < 2; ++t) {
                int tt = 2 * wc + t;
                bf16x8 br_ = *(const bf16x8*)(wFrag + (fb + (size_t)(tt) * 64 + lane) * 8);
                bf16x8 bz_ = *(const bf16x8*)(wFrag + (fb + (size_t)(8 + tt) * 64 + lane) * 8);
                bf16x8 bn_ = *(const bf16x8*)(wFrag + (fb + (size_t)(16 + tt) * 64 + lane) * 8);
                acc_r[0][t] = mfma_bf16(a0, br_, acc_r[0][t]);
                acc_r[1][t] = mfma_bf16(a1, br_, acc_r[1][t]);
                acc_z[0][t] = mfma_bf16(a0, bz_, acc_z[0][t]);
                acc_z[1][t] = mfma_bf16(a1, bz_, acc_z[1][t]);
                acc_hn[0][t] = mfma_bf16(a0, bn_, acc_hn[0][t]);
                acc_hn[1][t] = mfma_bf16(a1, bn_, acc_hn[1][t]);
            }
        }
    }

    // ---- epilogue: gate combine (fast activations) + bf16 store ----
    #pragma unroll
    for (int t = 0; t < 2; ++t) {
        int u = wc * 32 + t * 16 + l15;
        float br = bias[u];
        float bz = bias[128 + u];
        float bin = bias[256 + u];
        float bhn = bias[384 + u];
        #pragma unroll
        for (int rt = 0; rt < 2; ++rt) {
            float4 mv = *(const float4*)(maskg + Rb + rbase + rt * 16 + lg * 4);
            const float* mp = (const float*)&mv;
            #pragma unroll
            for (int reg = 0; reg < 4; ++reg) {
                int row = rbase + rt * 16 + lg * 4 + reg;
                int grow = Rb + row;
                float ar = acc_r[rt][t][reg] + br;
                float az = acc_z[rt][t][reg] + bz;
                float ain = acc_in[rt][t][reg] + bin;
                float ahn = acc_hn[rt][t][reg] + bhn;  // leaf: acc_hn==0 -> r*bhn, matches ref
                float rg = fast_sigmoid(ar);
                float zg = fast_sigmoid(az);
                float cg = fast_tanh(ain + rg * ahn);
                float h1 = 0.f, h2 = 0.f;
                if (!leaf) {
                    h1 = bf2f(a_lds[row * LDA + 32 + u]);
                    h2 = bf2f(a_lds[row * LDA + 160 + u]);
                }
                float ho = (1.f - zg) * cg + zg * 0.5f * (h1 + h2);
                out[(size_t)grow * H + u] = f2bf(ho * mp[reg]);
            }
        }
    }
}

// ---------------------------------------------------------------------------
// Final projection from bf16 root.
// ---------------------------------------------------------------------------
__global__ __launch_bounds__(128) void proj_kernel(
    const unsigned short* __restrict__ root,
    const float* __restrict__ mu_w, const float* __restrict__ mu_b,
    const float* __restrict__ lv_w, const float* __restrict__ lv_b,
    float* __restrict__ out)
{
    __shared__ float r_lds[H];
    int b = blockIdx.x;
    int j = threadIdx.x;
    r_lds[j] = bf2f(root[(size_t)b * H + j]);
    __syncthreads();
    float am = 0.f, al = 0.f;
    #pragma unroll 8
    for (int k = 0; k < H; ++k) {
        float rv = r_lds[k];
        am += rv * mu_w[(size_t)j * H + k];
        al += rv * lv_w[(size_t)j * H + k];
    }
    out[(size_t)b * H + j] = am + mu_b[j];
    out[(size_t)(B * H) + (size_t)b * H + j] = al + lv_b[j];
}

// ---------------------------------------------------------------------------
extern "C" void kernel_launch(void* const* d_in, const int* in_sizes, int n_in,
                              void* d_out, int out_size, void* d_ws, size_t ws_size,
                              hipStream_t stream)
{
    const float* targets = (const float*)d_in[0];
    const float* masks   = (const float*)d_in[1];
    const float* wir_w = (const float*)d_in[2];  const float* wir_b = (const float*)d_in[3];
    const float* whr_w = (const float*)d_in[4];  const float* whr_b = (const float*)d_in[5];
    const float* wiz_w = (const float*)d_in[6];  const float* wiz_b = (const float*)d_in[7];
    const float* whz_w = (const float*)d_in[8];  const float* whz_b = (const float*)d_in[9];
    const float* win_w = (const float*)d_in[10]; const float* win_b = (const float*)d_in[11];
    const float* whn_w = (const float*)d_in[12]; const float* whn_b = (const float*)d_in[13];
    const float* mu_w  = (const float*)d_in[14]; const float* mu_b  = (const float*)d_in[15];
    const float* lv_w  = (const float*)d_in[16]; const float* lv_b  = (const float*)d_in[17];

    unsigned short* bufA  = (unsigned short*)d_ws;          // even levels
    unsigned short* bufB  = bufA + 16777216;                // odd levels
    unsigned short* wFrag = bufB + 8388608;                 // 9*24*64*8 bf16
    float*          biasw = (float*)(wFrag + 110592);

    prep_pack<<<(9 * 24 * 64 + 255) / 256, 256, 0, stream>>>(
        wir_w, whr_w, wiz_w, whz_w, win_w, whn_w,
        wir_b, whr_b, wiz_b, whz_b, win_b, whn_b, wFrag, biasw);

    const unsigned short* prev = nullptr;
    for (int d = 10; d >= 0; --d) {
        int n = 1 << d;
        int start = n - 1;
        unsigned short* outb = (d & 1) ? bufB : bufA;
        int blocks = (n * B) / 64;
        gru_mfma_kernel<<<blocks, 512, 0, stream>>>(
            targets + (size_t)start * B * V,
            masks + (size_t)start * B,
            prev, outb, wFrag, biasw, prev == nullptr ? 1 : 0);
        prev = outb;
    }

    proj_kernel<<<128, 128, 0, stream>>>(bufA, mu_w, mu_b, lv_w, lv_b, (float*)d_out);
}